// Round 3
// baseline (185.910 us; speedup 1.0000x reference)
//
#include <hip/hip_runtime.h>

#define BLK 256
#define PD 64
#define PI_F 3.14159265358979323846f

__device__ __forceinline__ float fast_tanh(float v) {
    float e = __expf(2.0f * v);
    return 1.0f - 2.0f / (e + 1.0f);
}

// One thread = one batch element for the circuit; block-cooperative fp32 epilogue.
// Qubit w <-> bit (3-w) of the 4-bit amplitude index (C-order flatten of (2,2,2,2)).
extern "C" __global__ void __launch_bounds__(BLK)
qbranch_kernel(const float* __restrict__ x,      // (B,4)
               const float* __restrict__ wts,    // (2,4,3)
               const float* __restrict__ W,      // (64,4)
               const float* __restrict__ bias,   // (64)
               const float* __restrict__ gamma,  // (64)
               const float* __restrict__ beta,   // (64)
               float* __restrict__ out)          // (B,64) float32
{
    __shared__ float sg[64];        // 8 rot gates x (u00,u01,u10,u11) x (re,im)
    __shared__ float sS[20];        // LN moments: M(10 sym), v(4), Wbar(4), bbar, bsq
    __shared__ float sq[BLK][9];    // q0..q3, mu, rstd (stride 9 -> conflict-free)

    const int t = threadIdx.x;
    const int b = blockIdx.x * BLK + t;

    // ---- early global loads ----
    const float4 xv = reinterpret_cast<const float4*>(x)[b];
    const int p4 = t & 15;          // this thread's group of 4 output columns
    const float4 w0 = reinterpret_cast<const float4*>(W)[p4 * 4 + 0];
    const float4 w1 = reinterpret_cast<const float4*>(W)[p4 * 4 + 1];
    const float4 w2 = reinterpret_cast<const float4*>(W)[p4 * 4 + 2];
    const float4 w3 = reinterpret_cast<const float4*>(W)[p4 * 4 + 3];
    const float4 bg = reinterpret_cast<const float4*>(bias)[p4];
    const float4 gm = reinterpret_cast<const float4*>(gamma)[p4];
    const float4 bt = reinterpret_cast<const float4*>(beta)[p4];

    // ---- phase 0: wave 0 -> LN moments; wave 1 lanes 0..7 -> rot gates ----
    if (t < 64) {
        const float4 wr = reinterpret_cast<const float4*>(W)[t];
        const float bp = bias[t];
        float v[20] = { wr.x*wr.x, wr.x*wr.y, wr.x*wr.z, wr.x*wr.w,
                        wr.y*wr.y, wr.y*wr.z, wr.y*wr.w,
                        wr.z*wr.z, wr.z*wr.w,
                        wr.w*wr.w,
                        wr.x*bp, wr.y*bp, wr.z*bp, wr.w*bp,
                        wr.x, wr.y, wr.z, wr.w,
                        bp, bp*bp };
        #pragma unroll
        for (int o = 32; o > 0; o >>= 1) {
            #pragma unroll
            for (int k = 0; k < 20; ++k) v[k] += __shfl_xor(v[k], o, 64);
        }
        if (t == 0) {
            #pragma unroll
            for (int k = 0; k < 20; ++k) sS[k] = v[k] * (1.0f / 64.0f);
        }
    } else if (t < 72) {
        const int g = t - 64, l = g >> 2, w = g & 3;
        const float phi = wts[(l * 4 + w) * 3 + 0];
        const float th  = wts[(l * 4 + w) * 3 + 1];
        const float om  = wts[(l * 4 + w) * 3 + 2];
        float st, ct;  __sincosf(0.5f * th, &st, &ct);
        float sa, ca;  __sincosf(0.5f * (phi + om), &sa, &ca);
        float sb, cb;  __sincosf(0.5f * (phi - om), &sb, &cb);
        float* gg = &sg[g * 8];
        gg[0] =  ct * ca;  gg[1] = -ct * sa;   // u00 = ep*ct
        gg[2] = -st * cb;  gg[3] = -st * sb;   // u01 = -conj(em)*st
        gg[4] =  st * cb;  gg[5] = -st * sb;   // u10 = em*st
        gg[6] =  ct * ca;  gg[7] =  ct * sa;   // u11 = conj(ep)*ct
    }

    // ---- per-thread RX product-state init ----
    float cc[4], ss[4];
    {
        const float xs[4] = {xv.x, xv.y, xv.z, xv.w};
        #pragma unroll
        for (int w = 0; w < 4; ++w) {
            const float xt = fast_tanh(xs[w]) * PI_F;
            __sincosf(0.5f * xt, &ss[w], &cc[w]);
        }
    }
    // amp[i] = (-i)^popc(i) * prod_w (bit ? sin : cos)
    float ar[16], ai[16];
    #pragma unroll
    for (int i = 0; i < 16; ++i) {
        float m = 1.0f;
        #pragma unroll
        for (int w = 0; w < 4; ++w)
            m *= ((i >> (3 - w)) & 1) ? ss[w] : cc[w];
        const int k = __popc((unsigned)i) & 3;
        ar[i] = (k == 0) ? m : (k == 2 ? -m : 0.0f);
        ai[i] = (k == 1) ? -m : (k == 3 ? m : 0.0f);
    }

    __syncthreads();

    // ---- layers: 4 shared 1q gates + CNOT ring (fully unrolled, regs only) ----
    #pragma unroll
    for (int l = 0; l < 2; ++l) {
        #pragma unroll
        for (int w = 0; w < 4; ++w) {
            const float* gg = &sg[(l * 4 + w) * 8];
            const float u00r = gg[0], u00i = gg[1], u01r = gg[2], u01i = gg[3];
            const float u10r = gg[4], u10i = gg[5], u11r = gg[6], u11i = gg[7];
            const int m = 1 << (3 - w);
            #pragma unroll
            for (int i = 0; i < 16; ++i) {
                if (i & m) continue;
                const int j = i | m;
                const float a0r = ar[i], a0i = ai[i], a1r = ar[j], a1i = ai[j];
                ar[i] = u00r*a0r - u00i*a0i + u01r*a1r - u01i*a1i;
                ai[i] = u00r*a0i + u00i*a0r + u01r*a1i + u01i*a1r;
                ar[j] = u10r*a0r - u10i*a0i + u11r*a1r - u11i*a1i;
                ai[j] = u10r*a0i + u10i*a0r + u11r*a1i + u11i*a1r;
            }
        }
        const int r = (l == 0) ? 1 : 2;   // RANGES = {1,2}
        #pragma unroll
        for (int w = 0; w < 4; ++w) {
            const int cm = 1 << (3 - w);
            const int tq = (w + r) & 3;
            const int tm = 1 << (3 - tq);
            #pragma unroll
            for (int i = 0; i < 16; ++i) {
                if ((i & cm) && !(i & tm)) {
                    const int j = i | tm;
                    float tp;
                    tp = ar[i]; ar[i] = ar[j]; ar[j] = tp;
                    tp = ai[i]; ai[i] = ai[j]; ai[j] = tp;
                }
            }
        }
    }

    // ---- Z expectations, softmax ----
    float z0 = 0.f, z1 = 0.f, z2 = 0.f, z3 = 0.f;
    #pragma unroll
    for (int i = 0; i < 16; ++i) {
        const float p = ar[i]*ar[i] + ai[i]*ai[i];
        z0 += (i & 8) ? -p : p;
        z1 += (i & 4) ? -p : p;
        z2 += (i & 2) ? -p : p;
        z3 += (i & 1) ? -p : p;
    }
    const float mx = fmaxf(fmaxf(z0, z1), fmaxf(z2, z3));
    const float e0 = __expf(z0 - mx), e1 = __expf(z1 - mx);
    const float e2 = __expf(z2 - mx), e3 = __expf(z3 - mx);
    const float inv = 1.0f / (e0 + e1 + e2 + e3);
    const float q0 = e0 * inv, q1 = e1 * inv, q2 = e2 * inv, q3 = e3 * inv;

    // ---- LN stats via precomputed moments: mu = q.Wbar + bbar;
    //      E[h^2] = q^T M q + 2 q.v + bsq ----
    const float mu = fmaf(q0, sS[14], fmaf(q1, sS[15], fmaf(q2, sS[16], fmaf(q3, sS[17], sS[18]))));
    const float t0 = sS[0]*q0 + sS[1]*q1 + sS[2]*q2 + sS[3]*q3 + 2.0f*sS[10];
    const float t1 = sS[1]*q0 + sS[4]*q1 + sS[5]*q2 + sS[6]*q3 + 2.0f*sS[11];
    const float t2 = sS[2]*q0 + sS[5]*q1 + sS[7]*q2 + sS[8]*q3 + 2.0f*sS[12];
    const float t3 = sS[3]*q0 + sS[6]*q1 + sS[8]*q2 + sS[9]*q3 + 2.0f*sS[13];
    const float Eh2 = t0*q0 + t1*q1 + t2*q2 + t3*q3 + sS[19];
    const float var = Eh2 - mu * mu;
    const float rstd = rsqrtf(var + 1e-5f);

    sq[t][0] = q0; sq[t][1] = q1; sq[t][2] = q2; sq[t][3] = q3;
    sq[t][4] = mu; sq[t][5] = rstd;
    __syncthreads();

    // ---- phase 2: coalesced fp32 epilogue. Lane (t&15) owns 4 consecutive
    //      cols; wave w covers 4 consecutive rows per iter -> 1 KB contiguous
    //      per wave store issue. 16 iters cover the block's 256 rows. ----
    const int sub = t >> 4;
    const size_t base = (size_t)blockIdx.x * (BLK * PD);
    #pragma unroll 4
    for (int it = 0; it < 16; ++it) {
        const int row = it * 16 + sub;
        const float r0 = sq[row][0], r1 = sq[row][1], r2 = sq[row][2], r3 = sq[row][3];
        const float mur = sq[row][4], rsr = sq[row][5];
        const float h0 = fmaf(r0, w0.x, fmaf(r1, w0.y, fmaf(r2, w0.z, fmaf(r3, w0.w, bg.x))));
        const float h1 = fmaf(r0, w1.x, fmaf(r1, w1.y, fmaf(r2, w1.z, fmaf(r3, w1.w, bg.y))));
        const float h2 = fmaf(r0, w2.x, fmaf(r1, w2.y, fmaf(r2, w2.z, fmaf(r3, w2.w, bg.z))));
        const float h3 = fmaf(r0, w3.x, fmaf(r1, w3.y, fmaf(r2, w3.z, fmaf(r3, w3.w, bg.w))));
        float4 pk;
        pk.x = fmaf((h0 - mur), rsr * gm.x, bt.x);
        pk.y = fmaf((h1 - mur), rsr * gm.y, bt.y);
        pk.z = fmaf((h2 - mur), rsr * gm.z, bt.z);
        pk.w = fmaf((h3 - mur), rsr * gm.w, bt.w);
        *reinterpret_cast<float4*>(&out[base + (size_t)row * PD + p4 * 4]) = pk;
    }
}

extern "C" void kernel_launch(void* const* d_in, const int* in_sizes, int n_in,
                              void* d_out, int out_size, void* d_ws, size_t ws_size,
                              hipStream_t stream) {
    const float* x     = (const float*)d_in[0];
    const float* wts   = (const float*)d_in[1];
    const float* W     = (const float*)d_in[2];
    const float* bias  = (const float*)d_in[3];
    const float* gamma = (const float*)d_in[4];
    const float* beta  = (const float*)d_in[5];
    float* out = (float*)d_out;
    const int B = in_sizes[0] / 4;          // 524288
    hipLaunchKernelGGL(qbranch_kernel, dim3(B / BLK), dim3(BLK), 0, stream,
                       x, wts, W, bias, gamma, beta, out);
}

// Round 4
// 175.354 us; speedup vs baseline: 1.0602x; 1.0602x over previous
//
#include <hip/hip_runtime.h>

#define BLK 256
#define PD 64
#define PI_F 3.14159265358979323846f

__device__ __forceinline__ float fast_tanh(float v) {
    float e = __expf(2.0f * v);
    return 1.0f - 2.0f / (e + 1.0f);
}

// Apply 2x2 complex gate to qubit mask M over 16 amps (new_i = sum_j U[i][j] old_j).
template<int M>
__device__ __forceinline__ void gate_apply(float* ar, float* ai,
        float u00r, float u00i, float u01r, float u01i,
        float u10r, float u10i, float u11r, float u11i) {
    #pragma unroll
    for (int i = 0; i < 16; ++i) {
        if (i & M) continue;
        const int j = i | M;
        const float a0r = ar[i], a0i = ai[i], a1r = ar[j], a1i = ai[j];
        ar[i] = u00r*a0r - u00i*a0i + u01r*a1r - u01i*a1i;
        ai[i] = u00r*a0i + u00i*a0r + u01r*a1i + u01i*a1r;
        ar[j] = u10r*a0r - u10i*a0i + u11r*a1r - u11i*a1i;
        ai[j] = u10r*a0i + u10i*a0r + u11r*a1i + u11i*a1r;
    }
}

template<int CM, int TM>
__device__ __forceinline__ void cnotg(float* ar, float* ai) {
    #pragma unroll
    for (int i = 0; i < 16; ++i) {
        if ((i & CM) && !(i & TM)) {
            const int j = i | TM;
            float tp;
            tp = ar[i]; ar[i] = ar[j]; ar[j] = tp;
            tp = ai[i]; ai[i] = ai[j]; ai[j] = tp;
        }
    }
}

// ---- prep: 1 block x 64 threads. ws[0..63] = 8 gates x 8 coeffs;
//      ws[64..83] = LN moments {M(10 sym), v(4), Wbar(4), bbar, bsq} ----
extern "C" __global__ void __launch_bounds__(64)
qbranch_prep(const float* __restrict__ wts, const float* __restrict__ W,
             const float* __restrict__ bias, float* __restrict__ ws)
{
    const int t = threadIdx.x;
    const float4 wr = reinterpret_cast<const float4*>(W)[t];
    const float bp = bias[t];
    float v[20] = { wr.x*wr.x, wr.x*wr.y, wr.x*wr.z, wr.x*wr.w,
                    wr.y*wr.y, wr.y*wr.z, wr.y*wr.w,
                    wr.z*wr.z, wr.z*wr.w,
                    wr.w*wr.w,
                    wr.x*bp, wr.y*bp, wr.z*bp, wr.w*bp,
                    wr.x, wr.y, wr.z, wr.w,
                    bp, bp*bp };
    #pragma unroll
    for (int o = 32; o > 0; o >>= 1) {
        #pragma unroll
        for (int k = 0; k < 20; ++k) v[k] += __shfl_xor(v[k], o, 64);
    }
    if (t == 0) {
        #pragma unroll
        for (int k = 0; k < 20; ++k) ws[64 + k] = v[k] * (1.0f / 64.0f);
    }
    if (t < 8) {
        const float phi = wts[t * 3 + 0];
        const float th  = wts[t * 3 + 1];
        const float om  = wts[t * 3 + 2];
        float st, ct;  __sincosf(0.5f * th, &st, &ct);
        float sa, ca;  __sincosf(0.5f * (phi + om), &sa, &ca);
        float sb, cb;  __sincosf(0.5f * (phi - om), &sb, &cb);
        float* gg = ws + t * 8;
        gg[0] =  ct * ca;  gg[1] = -ct * sa;   // u00 = ep*ct
        gg[2] = -st * cb;  gg[3] = -st * sb;   // u01 = -conj(em)*st
        gg[4] =  st * cb;  gg[5] = -st * sb;   // u10 = em*st
        gg[6] =  ct * ca;  gg[7] =  ct * sa;   // u11 = conj(ep)*ct
    }
}

// ---- main: one thread per batch element; gates/moments via uniform (scalar)
//      loads from cw; block-cooperative coalesced fp32 epilogue. ----
extern "C" __global__ void __launch_bounds__(BLK)
qbranch_main(const float* __restrict__ x,      // (B,4)
             const float* __restrict__ W,      // (64,4)
             const float* __restrict__ bias,   // (64)
             const float* __restrict__ gamma,  // (64)
             const float* __restrict__ beta,   // (64)
             const float* __restrict__ cw,     // ws: 64 gate coeffs + 20 moments
             float* __restrict__ out)          // (B,64) fp32
{
    __shared__ float4 sq4[BLK];   // q0..q3 per row
    __shared__ float2 sms[BLK];   // mu, rstd per row

    const int t = threadIdx.x;
    const int b = blockIdx.x * BLK + t;
    const float4 xv = reinterpret_cast<const float4*>(x)[b];

    // ---- RX 2-vector per qubit, layer-0 rot folded in (product state) ----
    // RX|0> = (c, -i s); v = U * (c, -i s):
    //   v0 = (c*u00r + s*u01i) + i(c*u00i - s*u01r)
    //   v1 = (c*u10r + s*u11i) + i(c*u10i - s*u11r)
    float v0r[4], v0i[4], v1r[4], v1i[4];
    const float xs[4] = {xv.x, xv.y, xv.z, xv.w};
    #pragma unroll
    for (int w = 0; w < 4; ++w) {
        float s, c;
        __sincosf(0.5f * PI_F * fast_tanh(xs[w]), &s, &c);
        const float g0 = cw[w*8+0], g1 = cw[w*8+1], g2 = cw[w*8+2], g3 = cw[w*8+3];
        const float g4 = cw[w*8+4], g5 = cw[w*8+5], g6 = cw[w*8+6], g7 = cw[w*8+7];
        v0r[w] = fmaf(c, g0,  s * g3);
        v0i[w] = fmaf(c, g1, -s * g2);
        v1r[w] = fmaf(c, g4,  s * g7);
        v1i[w] = fmaf(c, g5, -s * g6);
    }

    // ---- build 16-amp state via pairwise tensor products ----
    // amp index i = (b0 b1 b2 b3), qubit w <-> bit (3-w).  A over (q0,q1), B over (q2,q3).
    float Ar[4], Ai[4], Br[4], Bi[4];
    #pragma unroll
    for (int j = 0; j < 4; ++j) {
        const int b0 = j >> 1, b1 = j & 1;
        const float p0r = b0 ? v1r[0] : v0r[0], p0i = b0 ? v1i[0] : v0i[0];
        const float p1r = b1 ? v1r[1] : v0r[1], p1i = b1 ? v1i[1] : v0i[1];
        Ar[j] = p0r*p1r - p0i*p1i;
        Ai[j] = p0r*p1i + p0i*p1r;
        const float p2r = b0 ? v1r[2] : v0r[2], p2i = b0 ? v1i[2] : v0i[2];
        const float p3r = b1 ? v1r[3] : v0r[3], p3i = b1 ? v1i[3] : v0i[3];
        Br[j] = p2r*p3r - p2i*p3i;
        Bi[j] = p2r*p3i + p2i*p3r;
    }
    float ar[16], ai[16];
    #pragma unroll
    for (int i = 0; i < 16; ++i) {
        const int hi = i >> 2, lo = i & 3;
        ar[i] = Ar[hi]*Br[lo] - Ai[hi]*Bi[lo];
        ai[i] = Ar[hi]*Bi[lo] + Ai[hi]*Br[lo];
    }

    // ---- CNOT ring r=1: (0,1),(1,2),(2,3),(3,0) ----
    cnotg<8, 4>(ar, ai);
    cnotg<4, 2>(ar, ai);
    cnotg<2, 1>(ar, ai);
    cnotg<1, 8>(ar, ai);

    // ---- layer 1 rot gates (entangled state, full apply; coeffs are SGPRs) ----
    gate_apply<8>(ar, ai, cw[32], cw[33], cw[34], cw[35], cw[36], cw[37], cw[38], cw[39]);
    gate_apply<4>(ar, ai, cw[40], cw[41], cw[42], cw[43], cw[44], cw[45], cw[46], cw[47]);
    gate_apply<2>(ar, ai, cw[48], cw[49], cw[50], cw[51], cw[52], cw[53], cw[54], cw[55]);
    gate_apply<1>(ar, ai, cw[56], cw[57], cw[58], cw[59], cw[60], cw[61], cw[62], cw[63]);

    // ---- CNOT ring r=2: (0,2),(1,3),(2,0),(3,1) ----
    cnotg<8, 2>(ar, ai);
    cnotg<4, 1>(ar, ai);
    cnotg<2, 8>(ar, ai);
    cnotg<1, 4>(ar, ai);

    // ---- Z expectations, softmax ----
    float z0 = 0.f, z1 = 0.f, z2 = 0.f, z3 = 0.f;
    #pragma unroll
    for (int i = 0; i < 16; ++i) {
        const float p = ar[i]*ar[i] + ai[i]*ai[i];
        z0 += (i & 8) ? -p : p;
        z1 += (i & 4) ? -p : p;
        z2 += (i & 2) ? -p : p;
        z3 += (i & 1) ? -p : p;
    }
    const float mx = fmaxf(fmaxf(z0, z1), fmaxf(z2, z3));
    const float e0 = __expf(z0 - mx), e1 = __expf(z1 - mx);
    const float e2 = __expf(z2 - mx), e3 = __expf(z3 - mx);
    const float inv = 1.0f / (e0 + e1 + e2 + e3);
    const float q0 = e0 * inv, q1 = e1 * inv, q2 = e2 * inv, q3 = e3 * inv;

    // ---- LN stats via moments: mu = q.Wbar + bbar; E[h^2] = q^T M q + 2 q.v + bsq ----
    const float* sS = cw + 64;
    const float mu = fmaf(q0, sS[14], fmaf(q1, sS[15], fmaf(q2, sS[16], fmaf(q3, sS[17], sS[18]))));
    const float t0 = sS[0]*q0 + sS[1]*q1 + sS[2]*q2 + sS[3]*q3 + 2.0f*sS[10];
    const float t1 = sS[1]*q0 + sS[4]*q1 + sS[5]*q2 + sS[6]*q3 + 2.0f*sS[11];
    const float t2 = sS[2]*q0 + sS[5]*q1 + sS[7]*q2 + sS[8]*q3 + 2.0f*sS[12];
    const float t3 = sS[3]*q0 + sS[6]*q1 + sS[8]*q2 + sS[9]*q3 + 2.0f*sS[13];
    const float Eh2 = t0*q0 + t1*q1 + t2*q2 + t3*q3 + sS[19];
    const float rstd = rsqrtf(Eh2 - mu * mu + 1e-5f);

    sq4[t] = make_float4(q0, q1, q2, q3);
    sms[t] = make_float2(mu, rstd);

    // ---- epilogue constants loaded late (short live range, L2-resident) ----
    const int p4 = t & 15;          // this thread's group of 4 output columns
    const float4 w0 = reinterpret_cast<const float4*>(W)[p4 * 4 + 0];
    const float4 w1 = reinterpret_cast<const float4*>(W)[p4 * 4 + 1];
    const float4 w2 = reinterpret_cast<const float4*>(W)[p4 * 4 + 2];
    const float4 w3 = reinterpret_cast<const float4*>(W)[p4 * 4 + 3];
    const float4 bg = reinterpret_cast<const float4*>(bias)[p4];
    const float4 gm = reinterpret_cast<const float4*>(gamma)[p4];
    const float4 bt = reinterpret_cast<const float4*>(beta)[p4];

    __syncthreads();

    // ---- coalesced epilogue: lane (t&15) owns 4 cols, 16 iters cover 256 rows;
    //      wave stores 1 KB contiguous per iter ----
    const int sub = t >> 4;
    const size_t base = (size_t)blockIdx.x * (BLK * PD);
    #pragma unroll 4
    for (int it = 0; it < 16; ++it) {
        const int row = it * 16 + sub;
        const float4 qv = sq4[row];
        const float2 ms = sms[row];
        const float h0 = fmaf(qv.x, w0.x, fmaf(qv.y, w0.y, fmaf(qv.z, w0.z, fmaf(qv.w, w0.w, bg.x))));
        const float h1 = fmaf(qv.x, w1.x, fmaf(qv.y, w1.y, fmaf(qv.z, w1.z, fmaf(qv.w, w1.w, bg.y))));
        const float h2 = fmaf(qv.x, w2.x, fmaf(qv.y, w2.y, fmaf(qv.z, w2.z, fmaf(qv.w, w2.w, bg.z))));
        const float h3 = fmaf(qv.x, w3.x, fmaf(qv.y, w3.y, fmaf(qv.z, w3.z, fmaf(qv.w, w3.w, bg.w))));
        float4 pk;
        pk.x = fmaf((h0 - ms.x), ms.y * gm.x, bt.x);
        pk.y = fmaf((h1 - ms.x), ms.y * gm.y, bt.y);
        pk.z = fmaf((h2 - ms.x), ms.y * gm.z, bt.z);
        pk.w = fmaf((h3 - ms.x), ms.y * gm.w, bt.w);
        *reinterpret_cast<float4*>(&out[base + (size_t)row * PD + p4 * 4]) = pk;
    }
}

extern "C" void kernel_launch(void* const* d_in, const int* in_sizes, int n_in,
                              void* d_out, int out_size, void* d_ws, size_t ws_size,
                              hipStream_t stream) {
    const float* x     = (const float*)d_in[0];
    const float* wts   = (const float*)d_in[1];
    const float* W     = (const float*)d_in[2];
    const float* bias  = (const float*)d_in[3];
    const float* gamma = (const float*)d_in[4];
    const float* beta  = (const float*)d_in[5];
    float* ws  = (float*)d_ws;
    float* out = (float*)d_out;
    const int B = in_sizes[0] / 4;          // 524288
    hipLaunchKernelGGL(qbranch_prep, dim3(1), dim3(64), 0, stream, wts, W, bias, ws);
    hipLaunchKernelGGL(qbranch_main, dim3(B / BLK), dim3(BLK), 0, stream,
                       x, W, bias, gamma, beta, ws, out);
}